// Round 7
// baseline (198.335 us; speedup 1.0000x reference)
//
#include <hip/hip_runtime.h>
#include <math.h>

// out[b] = (1^T · Π_d C_d · P) · Π_d x[b,d] + bias  — per-row scalars commute
// out of the batch-independent matrix chain. SINGLE fused kernel:
//   blocks 0..31   : fold 64-core chunks (LDS-staged), fan-in via flags,
//                    block 0 reduces in wave-0 registers, projects -> pE,
//                    release-stores pE-ready flag.
//   blocks 32..2079: one wave per row — issue the 64 MB of x-loads FIRST
//                    (independent of pE), wave-product, then acquire-spin on
//                    the pE flag (chain latency hides under the HBM read),
//                    epilogue out[b,o] = ldexp(p[o]*s_b, E) + bias[o].
// Liveness: in-order dispatch puts chain blocks on CUs first; grid ~fits
// co-resident. Flags re-poisoned (0xAA != MAGIC) by harness each replay.
// Row products underflow fp32 to 0 exactly as the reference (absmax 0.0,
// verified rounds 1/5/6).

#define DFEAT 2048
#define R 16
#define NR2 256               // R*R
#define OUTD 64
#define CHUNK 64              // cores folded per chain block
#define NCHUNK (DFEAT / CHUNK)    // 32 chain blocks
#define MAGIC 0x7E57C0DE

__global__ __launch_bounds__(256) void mps_fused(const float* __restrict__ cores,
                                                 const float* __restrict__ proj,
                                                 const float* __restrict__ x,
                                                 const float* __restrict__ bias,
                                                 float* __restrict__ out,
                                                 float* __restrict__ partials,
                                                 int* __restrict__ flags,
                                                 float* __restrict__ pE,
                                                 int B) {
    const int tid = threadIdx.x;

    if (blockIdx.x >= NCHUNK) {
        // =================== ROWS PART (one wave per row) ===================
        const int rbid = blockIdx.x - NCHUNK;
        const int row  = (rbid * 256 + tid) >> 6;
        const int lane = tid & 63;
        if (row >= B) return;

        // ---- phase 1: the compulsory 64 MB read — independent of pE ----
        const float4* xr = (const float4*)(x + (size_t)row * DFEAT);
        float prod = 1.f;
#pragma unroll
        for (int it = 0; it < DFEAT / (64 * 4); ++it) {   // 8 coalesced f4
            float4 v = xr[it * 64 + lane];
            prod *= (v.x * v.y) * (v.z * v.w);
        }
#pragma unroll
        for (int off = 32; off > 0; off >>= 1)            // wave-wide product
            prod *= __shfl_xor(prod, off);

        // ---- phase 2: wait for pE (usually already set), then epilogue ----
        while (__hip_atomic_load(&flags[0], __ATOMIC_ACQUIRE,
                                 __HIP_MEMORY_SCOPE_AGENT) != MAGIC)
            __builtin_amdgcn_s_sleep(2);

        const float pv = pE[lane];                        // lane < 64 == OUTD
        const int   E  = ((const int*)pE)[OUTD];
        out[(size_t)row * OUTD + lane] = ldexpf(pv * prod, E) + bias[lane];
        return;
    }

    // ====================== CHAIN PART (blocks 0..31) =======================
    __shared__ __align__(16) float Cs[CHUNK][R][R];   // 64 KB staged cores
    __shared__ float A[2][R][R];                      // running product
    __shared__ __align__(16) float Pt[NCHUNK][R][R];  // partials, TRANSPOSED
    const int i = tid >> 4, j = tid & 15;
    const size_t d0 = (size_t)blockIdx.x * CHUNK;

    // ---- stage this block's 64 cores: 4096 float4, 16/thread, coalesced ----
    const float4* g4 = (const float4*)(cores + d0 * NR2);
    float4* s4 = (float4*)&Cs[0][0][0];
#pragma unroll
    for (int q = 0; q < 16; ++q)
        s4[q * 256 + tid] = g4[q * 256 + tid];

    A[0][i][j] = (i == j) ? 1.f : 0.f;    // identity seed (exact)
    __syncthreads();                      // staging + A0 visible

    int cur = 0;
    for (int t = 0; t < CHUNK; ++t) {
        float acc = 0.f;
#pragma unroll
        for (int k = 0; k < R; ++k)
            acc = fmaf(A[cur][i][k], Cs[t][k][j], acc);
        A[cur ^ 1][i][j] = acc;           // own element only
        cur ^= 1;
        __syncthreads();
    }
    const float v = A[cur][i][j];         // this thread's partial element

    if (blockIdx.x != 0) {
        // ---- producer: publish partial, release flag ----
        partials[blockIdx.x * NR2 + tid] = v;
        __syncthreads();                  // block stores complete at L2
        if (tid == 0)
            __hip_atomic_store(&flags[blockIdx.x], MAGIC,
                               __ATOMIC_RELEASE, __HIP_MEMORY_SCOPE_AGENT);
        return;
    }

    // ---- block 0: own partial straight into LDS (transposed) ----
    Pt[0][j][i] = v;

    // acquire-spin for producers 1..31 (every thread: cache-inv side effect)
    {
        const int f = 1 + (tid % (NCHUNK - 1));
        while (__hip_atomic_load(&flags[f], __ATOMIC_ACQUIRE,
                                 __HIP_MEMORY_SCOPE_AGENT) != MAGIC) { }
    }
    __syncthreads();

    // ---- stage partials 1..31 into LDS transposed: 1984 float4 coalesced ---
#pragma unroll
    for (int q = 0; q < 8; ++q) {
        const int idx = q * 256 + tid;                // float4 index
        if (idx < (NCHUNK - 1) * 64) {
            float4 p4 = ((const float4*)(partials + NR2))[idx];
            const int flat = idx * 4;
            const int gg = (flat >> 8) + 1;           // which partial (1..31)
            const int e = flat & 255;
            const int k = e >> 4, j0 = e & 15;        // row k, cols j0..j0+3
            Pt[gg][j0 + 0][k] = p4.x;
            Pt[gg][j0 + 1][k] = p4.y;
            Pt[gg][j0 + 2][k] = p4.z;
            Pt[gg][j0 + 3][k] = p4.w;
        }
    }
    __syncthreads();

    // ---- wave-0 register fold: w <- w @ P_g, g = 0..31, no barriers ----
    if (tid < 64) {
        const int jj = tid & 15, q = tid >> 4;        // lane = jj + 16*q
        float w = 1.f;                                // w[jj], replicated in q
        int E = 0;
        for (int gg = 0; gg < NCHUNK; ++gg) {
            const float4 pr = *(const float4*)&Pt[gg][jj][4 * q];
            float s;
            s = __shfl(w, 4 * q + 0) * pr.x;          // w[k] lives at lane k
            s = fmaf(__shfl(w, 4 * q + 1), pr.y, s);
            s = fmaf(__shfl(w, 4 * q + 2), pr.z, s);
            s = fmaf(__shfl(w, 4 * q + 3), pr.w, s);
            s += __shfl_xor(s, 16);                   // sum the 4 q-groups
            s += __shfl_xor(s, 32);                   // -> nw[jj], replicated
            w = s;
            if ((gg & 7) == 7) {                      // exact pow2 renorm
                float m = fabsf(w);
#pragma unroll
                for (int off = 1; off <= 8; off <<= 1)
                    m = fmaxf(m, __shfl_xor(m, off));
                if (m > 0.f) {
                    int e = 0;
                    (void)frexpf(m, &e);              // m = f*2^e, f in [.5,1)
                    w = ldexpf(w, -e);                // exact rescale
                    E += e;
                }
            }
        }
        // p[o] = sum_k w[k] * proj[k][o]
        float p = 0.f;
#pragma unroll
        for (int k = 0; k < R; ++k)
            p = fmaf(__shfl(w, k), proj[k * OUTD + tid], p);
        pE[tid] = p;
        if (tid == 0) ((int*)pE)[OUTD] = E;
        // release pE-ready: tid 0..63 are ONE wave, so tid0's release-store
        // orders after this wave's pE stores (vmcnt drained by the fence)
        if (tid == 0)
            __hip_atomic_store(&flags[0], MAGIC,
                               __ATOMIC_RELEASE, __HIP_MEMORY_SCOPE_AGENT);
    }
}

// ---------------------------------------------------------------------------
extern "C" void kernel_launch(void* const* d_in, const int* in_sizes, int n_in,
                              void* d_out, int out_size, void* d_ws, size_t ws_size,
                              hipStream_t stream) {
    const float* inputs = (const float*)d_in[0];   // (B, 2048) fp32
    const float* cores  = (const float*)d_in[1];   // (2048, 16, 16) fp32
    const float* proj   = (const float*)d_in[2];   // (16, 64) fp32
    const float* bias   = (const float*)d_in[3];   // (64,) fp32
    float* out = (float*)d_out;                    // (B, 64) fp32

    // ws layout (16B aligned): partials | pE (64f + int E, padded) | flags
    float* partials = (float*)d_ws;                // 32*256 floats (32 KiB)
    float* pE    = partials + NCHUNK * NR2;        // 64 floats + int E (+pad)
    int*   flags = (int*)(pE + 68);                // 32 ints; 0xAA poison
                                                   // != MAGIC each replay

    const int B = in_sizes[0] / DFEAT;             // 8192

    const int rowBlocks = (B * 64 + 255) / 256;    // 2048
    mps_fused<<<NCHUNK + rowBlocks, 256, 0, stream>>>(
        cores, proj, inputs, bias, out, partials, flags, pE, B);
}